// Round 11
// baseline (124.078 us; speedup 1.0000x reference)
//
#include <hip/hip_runtime.h>
#include <hip/hip_bf16.h>
#include <math.h>

#define N_ROWS 32768
#define C_DIM 256
#define K_CODES 1024
#define DECAY_F 0.99f
#define ONE_MINUS_DECAY 0.01f
#define EPS_F 1e-5f

// Output offsets (floats)
#define OFF_QST 0
#define OFF_EMB 8388608
#define OFF_CS  8650752
#define OFF_DW  8651776
#define OFF_LOSS 8913920
#define OFF_PERP 8913921

// Workspace layout (float offsets)
#define WS_ESQ   0         // 1024
#define WS_BP    1024      // 131072 floats = 512KB bf16-packed E
#define WS_DWT   132096    // 262144  dwT[k][c]
#define WS_CNT   394240    // 1024
#define WS_LOSSP 395264    // 1024
#define WS_INVSM 396288    // 1024
#define WS_KEYS  397312    // 65536 floats = 32768 u64 argmax keys
#define WS_IDX   462848    // 32768 ints

typedef __attribute__((ext_vector_type(8))) short bf16x8;
typedef __attribute__((ext_vector_type(4))) float f32x4;
typedef union { short s[8]; unsigned u[4]; bf16x8 v; } fragu;

__device__ inline unsigned bf16rne(float f) {
    unsigned u = __float_as_uint(f);
    return (u + 0x7fffu + ((u >> 16) & 1u)) >> 16;
}

__device__ inline unsigned pack_bf16_pair(float a, float b) {
    float2 f2; f2.x = a; f2.y = b;
    __hip_bfloat162 h = __float22bfloat162_rn(f2);   // v_cvt_pk_bf16_f32
    union { __hip_bfloat162 b2; unsigned u; } cv;
    cv.b2 = h;
    return cv.u;
}

// monotone float->uint mapping (preserves order incl. negatives)
__device__ inline unsigned sortable_f32(float f) {
    unsigned u = __float_as_uint(f);
    return (u & 0x80000000u) ? ~u : (u | 0x80000000u);
}

// ---------------- prep (fused): pack E + esq + zero keys ----------------
// Blocks 0..127: pack group g = ct*8+ks (lane l: col=ct*16+(l&15),
// k=ks*32+(l>>4)*8+b) AND zero 256 keys each (covers all 32768).
// Blocks 128..131: esq[k] = sum_d E[d,k]^2 (fp32 exact).
__global__ __launch_bounds__(256) void prep_kernel(const float* __restrict__ E,
                                                   short* __restrict__ Bp,
                                                   float* __restrict__ esq,
                                                   unsigned long long* __restrict__ keys) {
    int tid = threadIdx.x;
    int b = blockIdx.x;
    if (b < 128) {
        keys[b * 256 + tid] = 0ull;
        int g = b * 4 + (tid >> 6);
        int l = tid & 63;
        int ct = g >> 3, ks = g & 7;
        int j = ct * 16 + (l & 15);
        int kbase = ks * 32 + (l >> 4) * 8;
        fragu out;
        #pragma unroll
        for (int q = 0; q < 8; ++q)
            out.s[q] = (short)bf16rne(E[(kbase + q) * K_CODES + j]);
        *(bf16x8*)(Bp + ((size_t)g * 64 + l) * 8) = out.v;
    } else {
        int k = (b - 128) * 256 + tid;
        float s = 0.f;
        #pragma unroll 8
        for (int d = 0; d < C_DIM; ++d) {
            float e = E[d * K_CODES + k];
            s += e * e;
        }
        esq[k] = s;
    }
}

// ---------------- MFMA distance + fused argmax, L2-direct B ----------------
// 512 blocks x 4 waves (256 thr), barrier-free. Logical block lb (XCD-swizzled
// so chalf pairs share an XCD's L2 for X): chalf = lb&1, brow = lb>>1.
// Wave w = rows brow*128 + w*32 .. +31 (2 row-tiles), cols chalf*512..+511.
// A (bf16) in registers; B-fragments read directly from L2-resident Bp
// (512KB, cached per-XCD). No LDS, no barriers -> compiler pipelines loads.
// Cross-chalf argmax merge via sortable-key atomicMax (deterministic).
__global__ __launch_bounds__(256) void mfma_dist_kernel(
    const float* __restrict__ X,
    const short* __restrict__ Bp,
    const float* __restrict__ esq,
    unsigned long long* __restrict__ keys)
{
    int tid = threadIdx.x;
    int w = tid >> 6, l = tid & 63;
    // XCD swizzle: dispatch d -> XCD d%8 (round robin); give each XCD a
    // contiguous run of 64 logical blocks = 32 brows with BOTH col-halves.
    int lb = (blockIdx.x & 7) * 64 + (blockIdx.x >> 3);
    int chalf = lb & 1;
    int row0 = (lb >> 1) * 128 + w * 32;
    int arow = l & 15;
    int aseg = l >> 4;
    const float* Xr0 = X + (size_t)(row0 + arow) * C_DIM + aseg * 8;
    const float* Xr1 = Xr0 + 16 * C_DIM;

    // ---- load + convert all A fragments once ----
    bf16x8 ahs0[8], ahs1[8];
    #pragma unroll
    for (int ks = 0; ks < 8; ++ks) {
        float xf0[8], xf1[8];
        *(float4*)(xf0)     = *(const float4*)(Xr0 + ks * 32);
        *(float4*)(xf0 + 4) = *(const float4*)(Xr0 + ks * 32 + 4);
        *(float4*)(xf1)     = *(const float4*)(Xr1 + ks * 32);
        *(float4*)(xf1 + 4) = *(const float4*)(Xr1 + ks * 32 + 4);
        fragu a0, a1;
        #pragma unroll
        for (int p = 0; p < 4; ++p) {
            a0.u[p] = pack_bf16_pair(xf0[2 * p], xf0[2 * p + 1]);
            a1.u[p] = pack_bf16_pair(xf1[2 * p], xf1[2 * p + 1]);
        }
        ahs0[ks] = a0.v;
        ahs1[ks] = a1.v;
    }

    float best[8];
    int bidx[8];
    #pragma unroll
    for (int i = 0; i < 8; ++i) { best[i] = -INFINITY; bidx[i] = 0; }

    // per-lane B base: group g = ct*8 + ks, element (g*64+l)*8
    const short* bl8 = Bp + (size_t)l * 8;

    #pragma unroll
    for (int cc = 0; cc < 4; ++cc) {
        f32x4 acc[2][8];
        #pragma unroll
        for (int rt = 0; rt < 2; ++rt)
            #pragma unroll
            for (int j = 0; j < 8; ++j)
                acc[rt][j] = (f32x4)(0.f);

        int ct0 = chalf * 32 + cc * 8;
        #pragma unroll
        for (int ks = 0; ks < 8; ++ks) {
            const short* bb = bl8 + ((size_t)(ct0 * 8 + ks)) * 512;
            #pragma unroll
            for (int j = 0; j < 8; ++j) {
                bf16x8 bh = *(const bf16x8*)(bb + j * 4096);   // next ct: +8 groups
                acc[0][j] = __builtin_amdgcn_mfma_f32_16x16x32_bf16(ahs0[ks], bh, acc[0][j], 0, 0, 0);
                acc[1][j] = __builtin_amdgcn_mfma_f32_16x16x32_bf16(ahs1[ks], bh, acc[1][j], 0, 0, 0);
            }
        }
        // epilogue for this 128-col chunk
        #pragma unroll
        for (int rt = 0; rt < 2; ++rt) {
            #pragma unroll
            for (int j = 0; j < 8; ++j) {
                int col = chalf * 512 + cc * 128 + j * 16 + (l & 15);
                float sq = esq[col];
                #pragma unroll
                for (int v = 0; v < 4; ++v) {
                    float s2 = 2.f * acc[rt][j][v] - sq;
                    int bi = rt * 4 + v;
                    if (s2 > best[bi]) { best[bi] = s2; bidx[bi] = col; }
                }
            }
        }
    }

    // reduce across the 16 lanes holding different cols of the same rows,
    // then merge col-halves via atomicMax on sortable key (min-idx ties).
    #pragma unroll
    for (int bi = 0; bi < 8; ++bi) {
        float bv = best[bi]; int ix = bidx[bi];
        #pragma unroll
        for (int m = 1; m < 16; m <<= 1) {
            float ov = __shfl_xor(bv, m, 64);
            int oi = __shfl_xor(ix, m, 64);
            if (ov > bv || (ov == bv && oi < ix)) { bv = ov; ix = oi; }
        }
        if ((l & 15) == 0) {
            int row = row0 + (bi >> 2) * 16 + aseg * 4 + (bi & 3);
            unsigned long long key =
                ((unsigned long long)sortable_f32(bv) << 32) |
                (unsigned long long)(0xffffffffu - (unsigned)ix);
            atomicMax(&keys[row], key);
        }
    }
}

// ---------------- convert keys -> int idx (after all dist blocks) ---------
__global__ __launch_bounds__(256) void convert_kernel(
    const unsigned long long* __restrict__ keys,
    int* __restrict__ idxbuf) {
    int i = blockIdx.x * 256 + threadIdx.x;
    idxbuf[i] = (int)(0xffffffffu - (unsigned)(keys[i] & 0xffffffffull));
}

// ---------------- per-code: quant_st, dw, counts, loss (no fp atomics) ----
#define QCAP 2048
__global__ __launch_bounds__(256) void percode_kernel(
    const float* __restrict__ X,
    const float* __restrict__ E,
    const int* __restrict__ idxbuf,
    float* __restrict__ out_qst,
    float* __restrict__ dwT,
    float* __restrict__ counts,
    float* __restrict__ lossp)
{
    __shared__ int queue[4][QCAP];
    __shared__ float redA[4][256];
    __shared__ float redL[4];
    __shared__ int redC[4];

    int k = blockIdx.x;
    int tid = threadIdx.x;
    int w = tid >> 6, lane = tid & 63;

    float q0 = E[(lane * 4 + 0) * K_CODES + k];
    float q1 = E[(lane * 4 + 1) * K_CODES + k];
    float q2 = E[(lane * 4 + 2) * K_CODES + k];
    float q3 = E[(lane * 4 + 3) * K_CODES + k];

    const float4* X4 = (const float4*)X;
    float4* O4 = (float4*)out_qst;
    const int4* I4 = (const int4*)idxbuf;

    float a0 = 0.f, a1 = 0.f, a2 = 0.f, a3 = 0.f, ls = 0.f;
    int tot = 0, cnt = 0;
    unsigned long long below_mask = (lane == 0) ? 0ull : (~0ull >> (64 - lane));

#define DRAIN() do {                                                        \
        for (int qi = 0; qi < cnt; ++qi) {                                  \
            int row = queue[w][qi];                                         \
            float4 x = X4[(size_t)row * 64 + lane];                         \
            float d0 = q0 - x.x, d1 = q1 - x.y, d2 = q2 - x.z, d3 = q3 - x.w; \
            float4 o; o.x = x.x + d0; o.y = x.y + d1;                       \
            o.z = x.z + d2; o.w = x.w + d3;                                 \
            O4[(size_t)row * 64 + lane] = o;                                \
            a0 += x.x; a1 += x.y; a2 += x.z; a3 += x.w;                     \
            ls += d0 * d0 + d1 * d1 + d2 * d2 + d3 * d3;                    \
        }                                                                   \
        tot += cnt; cnt = 0;                                                \
    } while (0)

    int base = w * 2048;   // int4 units; wave quarter = 8192 ints
    for (int it = 0; it < 32; ++it) {
        int4 v = I4[base + it * 64 + lane];
        int rbase = (base + it * 64 + lane) * 4;
        #pragma unroll
        for (int j = 0; j < 4; ++j) {
            int vj = (j == 0) ? v.x : (j == 1) ? v.y : (j == 2) ? v.z : v.w;
            bool p = (vj == k);
            unsigned long long mask = __ballot(p);
            if (p) queue[w][cnt + __popcll(mask & below_mask)] = rbase + j;
            cnt += __popcll(mask);
        }
        if (cnt >= QCAP - 256) DRAIN();
    }
    DRAIN();
#undef DRAIN

    redA[w][lane * 4 + 0] = a0;
    redA[w][lane * 4 + 1] = a1;
    redA[w][lane * 4 + 2] = a2;
    redA[w][lane * 4 + 3] = a3;
    #pragma unroll
    for (int m = 1; m < 64; m <<= 1) ls += __shfl_xor(ls, m, 64);
    if (lane == 0) { redL[w] = ls; redC[w] = tot; }
    __syncthreads();

    float dw = redA[0][tid] + redA[1][tid] + redA[2][tid] + redA[3][tid];
    dwT[(size_t)k * C_DIM + tid] = dw;
    if (tid == 0) {
        lossp[k] = redL[0] + redL[1] + redL[2] + redL[3];
        counts[k] = (float)(redC[0] + redC[1] + redC[2] + redC[3]);
    }
}

// ---------------- finalize 1: cs EMA, n, smoothing, entropy, loss ---------
__global__ __launch_bounds__(1024) void finalize1_kernel(const float* __restrict__ ema_cs,
                                                         const float* __restrict__ counts,
                                                         const float* __restrict__ lossp,
                                                         float* __restrict__ out,
                                                         float* __restrict__ inv_sm) {
    __shared__ double partN[16], partE[16], partL[16];
    __shared__ float nf_sh;
    int k = threadIdx.x;
    int lane = k & 63, wid = k >> 6;

    float cs = counts[k];
    float necs = ema_cs[k] * DECAY_F + cs * ONE_MINUS_DECAY;
    out[OFF_CS + k] = necs;

    double vn = (double)necs;
    float avg = cs * (1.0f / (float)N_ROWS);
    double ve = (double)(avg * logf(avg + 1e-10f));
    double vl = (double)lossp[k];
    #pragma unroll
    for (int m = 1; m < 64; m <<= 1) {
        vn += __shfl_xor(vn, m, 64);
        ve += __shfl_xor(ve, m, 64);
        vl += __shfl_xor(vl, m, 64);
    }
    if (lane == 0) { partN[wid] = vn; partE[wid] = ve; partL[wid] = vl; }
    __syncthreads();
    if (k == 0) {
        double sn = 0.0, se = 0.0, sl = 0.0;
        #pragma unroll
        for (int i = 0; i < 16; ++i) { sn += partN[i]; se += partE[i]; sl += partL[i]; }
        nf_sh = (float)sn;
        double eloss = sl / (double)(N_ROWS * C_DIM);
        out[OFF_LOSS] = (float)(0.25 * eloss);
        out[OFF_PERP] = expf((float)(-se));
    }
    __syncthreads();
    float nf = nf_sh;
    float sm = (necs + EPS_F) / (nf + (float)K_CODES * EPS_F) * nf;
    inv_sm[k] = 1.0f / sm;
}

// ---------------- finalize 2: new_ema_dw, new_embeddings ----------------
__global__ __launch_bounds__(256) void finalize2_kernel(const float* __restrict__ ema_dw,
                                                        const float* __restrict__ dwT,
                                                        const float* __restrict__ inv_sm,
                                                        float* __restrict__ out) {
    int i = blockIdx.x * 256 + threadIdx.x;
    int c = i >> 10;
    int k = i & 1023;
    float ndw = ema_dw[i] * DECAY_F + dwT[k * C_DIM + c] * ONE_MINUS_DECAY;
    out[OFF_DW + i] = ndw;
    out[OFF_EMB + i] = ndw * inv_sm[k];
}

extern "C" void kernel_launch(void* const* d_in, const int* in_sizes, int n_in,
                              void* d_out, int out_size, void* d_ws, size_t ws_size,
                              hipStream_t stream) {
    const float* inputs = (const float*)d_in[0];
    const float* E      = (const float*)d_in[1];
    const float* ema_cs = (const float*)d_in[2];
    const float* ema_dw = (const float*)d_in[3];
    float* out = (float*)d_out;
    float* ws  = (float*)d_ws;

    float* esq    = ws + WS_ESQ;
    short* Bp     = (short*)(ws + WS_BP);
    float* dwT    = ws + WS_DWT;
    float* counts = ws + WS_CNT;
    float* lossp  = ws + WS_LOSSP;
    float* inv_sm = ws + WS_INVSM;
    unsigned long long* keys = (unsigned long long*)(ws + WS_KEYS);
    int*   idxbuf = (int*)(ws + WS_IDX);

    prep_kernel<<<132, 256, 0, stream>>>(E, Bp, esq, keys);
    mfma_dist_kernel<<<512, 256, 0, stream>>>(inputs, Bp, esq, keys);
    convert_kernel<<<128, 256, 0, stream>>>(keys, idxbuf);
    percode_kernel<<<K_CODES, 256, 0, stream>>>(inputs, E, idxbuf, out + OFF_QST,
                                                dwT, counts, lossp);
    finalize1_kernel<<<1, 1024, 0, stream>>>(ema_cs, counts, lossp, out, inv_sm);
    finalize2_kernel<<<(C_DIM * K_CODES) / 256, 256, 0, stream>>>(ema_dw, dwT, inv_sm, out);
}

// Round 12
// 79.955 us; speedup vs baseline: 1.5518x; 1.5518x over previous
//
#include <hip/hip_runtime.h>
#include <hip/hip_bf16.h>
#include <math.h>

#define N_ROWS 32768
#define C_DIM 256
#define K_CODES 1024
#define DECAY_F 0.99f
#define ONE_MINUS_DECAY 0.01f
#define EPS_F 1e-5f

// Output offsets (floats)
#define OFF_QST 0
#define OFF_EMB 8388608
#define OFF_CS  8650752
#define OFF_DW  8651776
#define OFF_LOSS 8913920
#define OFF_PERP 8913921

// Workspace layout (float offsets)
#define WS_ESQ   0         // 1024
#define WS_BP    1024      // 131072 floats = 512KB bf16-packed E
#define WS_CNT   394240    // 1024
#define WS_LOSSP 395264    // 256
#define WS_NBUF  396288    // 1
#define WS_KEYS  397312    // 65536 floats = 32768 u64 argmax keys

typedef __attribute__((ext_vector_type(8))) short bf16x8;
typedef __attribute__((ext_vector_type(4))) float f32x4;
typedef union { short s[8]; unsigned u[4]; bf16x8 v; } fragu;

#define GLD_LDS16(g, l) __builtin_amdgcn_global_load_lds( \
    (const __attribute__((address_space(1))) void*)(g),   \
    (__attribute__((address_space(3))) void*)(l), 16, 0, 0)

__device__ inline unsigned bf16rne(float f) {
    unsigned u = __float_as_uint(f);
    return (u + 0x7fffu + ((u >> 16) & 1u)) >> 16;
}

__device__ inline unsigned pack_bf16_pair(float a, float b) {
    float2 f2; f2.x = a; f2.y = b;
    __hip_bfloat162 h = __float22bfloat162_rn(f2);   // v_cvt_pk_bf16_f32
    union { __hip_bfloat162 b2; unsigned u; } cv;
    cv.b2 = h;
    return cv.u;
}

// monotone float->uint mapping (preserves order incl. negatives)
__device__ inline unsigned sortable_f32(float f) {
    unsigned u = __float_as_uint(f);
    return (u & 0x80000000u) ? ~u : (u | 0x80000000u);
}

// ---------------- prep (fused): pack E + esq + zero keys + n --------------
// Blocks 0..127: pack group g = ct*8+ks (lane l: col=ct*16+(l&15),
// k=ks*32+(l>>4)*8+b) AND zero 256 keys each.
// Blocks 128..131: esq[k].  Block 132: n = 0.99*sum(ema_cs) + 0.01*N_ROWS
// (sum(cluster_size) == N_ROWS identically, so n is known before counting).
__global__ __launch_bounds__(256) void prep_kernel(const float* __restrict__ E,
                                                   const float* __restrict__ ema_cs,
                                                   short* __restrict__ Bp,
                                                   float* __restrict__ esq,
                                                   unsigned long long* __restrict__ keys,
                                                   float* __restrict__ nbuf) {
    int tid = threadIdx.x;
    int b = blockIdx.x;
    if (b < 128) {
        keys[b * 256 + tid] = 0ull;
        int g = b * 4 + (tid >> 6);
        int l = tid & 63;
        int ct = g >> 3, ks = g & 7;
        int j = ct * 16 + (l & 15);
        int kbase = ks * 32 + (l >> 4) * 8;
        fragu out;
        #pragma unroll
        for (int q = 0; q < 8; ++q)
            out.s[q] = (short)bf16rne(E[(kbase + q) * K_CODES + j]);
        *(bf16x8*)(Bp + ((size_t)g * 64 + l) * 8) = out.v;
    } else if (b < 132) {
        int k = (b - 128) * 256 + tid;
        float s = 0.f;
        #pragma unroll 8
        for (int d = 0; d < C_DIM; ++d) {
            float e = E[d * K_CODES + k];
            s += e * e;
        }
        esq[k] = s;
    } else {
        __shared__ float part[4];
        float4 v = *(const float4*)&ema_cs[tid * 4];
        float s = v.x + v.y + v.z + v.w;
        #pragma unroll
        for (int m = 1; m < 64; m <<= 1) s += __shfl_xor(s, m, 64);
        if ((tid & 63) == 0) part[tid >> 6] = s;
        __syncthreads();
        if (tid == 0)
            nbuf[0] = DECAY_F * (part[0] + part[1] + part[2] + part[3])
                      + ONE_MINUS_DECAY * (float)N_ROWS;
    }
}

// ---------------- MFMA distance + fused argmax (r9-proven ring) -----------
// 512 blocks x 4 waves. Block = 128 rows x 512 cols (chalf=bid&1).
// Wave w owns rows w*32..+31 (rt=2 row-tiles); all waves share cols.
// A (bf16) in registers. Phases p = cc*8+ks: 8KB stage into 5-slot LDS ring,
// depth-3 in flight, vmcnt(6), ONE barrier/phase.
// Cross-chalf argmax merge via sortable-key atomicMax (deterministic).
__global__ __launch_bounds__(256) void mfma_dist_kernel(
    const float* __restrict__ X,
    const short* __restrict__ Bp,
    const float* __restrict__ esq,
    unsigned long long* __restrict__ keys)
{
    __shared__ short sB[5][4096];    // 5 x 8KB ring

    int tid = threadIdx.x;
    int w = tid >> 6, l = tid & 63;
    int brow = blockIdx.x >> 1;
    int chalf = blockIdx.x & 1;
    int row0 = brow * 128 + w * 32;
    int arow = l & 15;
    int aseg = l >> 4;
    const float* Xr0 = X + (size_t)(row0 + arow) * C_DIM + aseg * 8;
    const float* Xr1 = Xr0 + 16 * C_DIM;

#define STAGE(cc_, ks_, sl) do {                                             \
        _Pragma("unroll")                                                    \
        for (int i = 0; i < 2; ++i) {                                        \
            int q = i * 4 + w;                                               \
            int ctg = chalf * 32 + (cc_) * 8 + q;                            \
            const short* src = Bp + ((size_t)(ctg * 8 + (ks_)) * 64 + l) * 8;\
            GLD_LDS16(src, &sB[sl][q * 512]);                                 \
        }                                                                    \
    } while (0)

    STAGE(0, 0, 0);
    STAGE(0, 1, 1);
    STAGE(0, 2, 2);

    // load + convert all A fragments (once); the compiler's waits on these
    // X loads drain vmcnt, so stages 0-2 are retired before the phase loop.
    bf16x8 ahs0[8], ahs1[8];
    #pragma unroll
    for (int ks = 0; ks < 8; ++ks) {
        float xf0[8], xf1[8];
        *(float4*)(xf0)     = *(const float4*)(Xr0 + ks * 32);
        *(float4*)(xf0 + 4) = *(const float4*)(Xr0 + ks * 32 + 4);
        *(float4*)(xf1)     = *(const float4*)(Xr1 + ks * 32);
        *(float4*)(xf1 + 4) = *(const float4*)(Xr1 + ks * 32 + 4);
        fragu a0, a1;
        #pragma unroll
        for (int p = 0; p < 4; ++p) {
            a0.u[p] = pack_bf16_pair(xf0[2 * p], xf0[2 * p + 1]);
            a1.u[p] = pack_bf16_pair(xf1[2 * p], xf1[2 * p + 1]);
        }
        ahs0[ks] = a0.v;
        ahs1[ks] = a1.v;
    }

    float best[8];
    int bidx[8];
    #pragma unroll
    for (int i = 0; i < 8; ++i) { best[i] = -INFINITY; bidx[i] = 0; }

    #pragma unroll
    for (int cc = 0; cc < 4; ++cc) {
        f32x4 acc[2][8];
        #pragma unroll
        for (int rt = 0; rt < 2; ++rt)
            #pragma unroll
            for (int j = 0; j < 8; ++j)
                acc[rt][j] = (f32x4)(0.f);

        #pragma unroll
        for (int ks = 0; ks < 8; ++ks) {
            const int p = cc * 8 + ks;
            const int slot = p % 5;
            if (p < 29) {
                const int pn = p + 3;
                STAGE(pn >> 3, pn & 7, pn % 5);
            }
            if (p < 29)       asm volatile("s_waitcnt vmcnt(6)" ::: "memory");
            else if (p == 29) asm volatile("s_waitcnt vmcnt(4)" ::: "memory");
            else if (p == 30) asm volatile("s_waitcnt vmcnt(2)" ::: "memory");
            else              asm volatile("s_waitcnt vmcnt(0)" ::: "memory");
            __builtin_amdgcn_s_barrier();
            asm volatile("" ::: "memory");

            const short* lbase = &sB[slot][l * 8];
            __builtin_amdgcn_s_setprio(1);
            #pragma unroll
            for (int j = 0; j < 8; ++j) {
                bf16x8 bh = *(const bf16x8*)(lbase + j * 512);
                acc[0][j] = __builtin_amdgcn_mfma_f32_16x16x32_bf16(ahs0[ks], bh, acc[0][j], 0, 0, 0);
                acc[1][j] = __builtin_amdgcn_mfma_f32_16x16x32_bf16(ahs1[ks], bh, acc[1][j], 0, 0, 0);
            }
            __builtin_amdgcn_s_setprio(0);
        }
        #pragma unroll
        for (int rt = 0; rt < 2; ++rt) {
            #pragma unroll
            for (int j = 0; j < 8; ++j) {
                int col = chalf * 512 + cc * 128 + j * 16 + (l & 15);
                float sq = esq[col];
                #pragma unroll
                for (int v = 0; v < 4; ++v) {
                    float s2 = 2.f * acc[rt][j][v] - sq;
                    int bi = rt * 4 + v;
                    if (s2 > best[bi]) { best[bi] = s2; bidx[bi] = col; }
                }
            }
        }
    }
#undef STAGE

    #pragma unroll
    for (int bi = 0; bi < 8; ++bi) {
        float bv = best[bi]; int ix = bidx[bi];
        #pragma unroll
        for (int m = 1; m < 16; m <<= 1) {
            float ov = __shfl_xor(bv, m, 64);
            int oi = __shfl_xor(ix, m, 64);
            if (ov > bv || (ov == bv && oi < ix)) { bv = ov; ix = oi; }
        }
        if ((l & 15) == 0) {
            int row = row0 + (bi >> 2) * 16 + aseg * 4 + (bi & 3);
            unsigned long long key =
                ((unsigned long long)sortable_f32(bv) << 32) |
                (unsigned long long)(0xffffffffu - (unsigned)ix);
            atomicMax(&keys[row], key);
        }
    }
}

// ---------------- per-4-codes: quant_st, DW, EMB, CS, counts, loss --------
// 256 blocks x 8 waves (512 thr); block owns codes k0..k0+3. Each wave scans
// 1/8 of keys, queues matching rows (entry = row*4+slot, ballot-prefix,
// deterministic), drains with a wave-uniform slot branch. Epilogue computes
// new_ema_dw and new_embeddings directly (n precomputed in prep) -> no
// finalize2 pass; scan traffic 4x lower than one-code-per-block.
#define QCAP 1024
__global__ __launch_bounds__(512) void percode_kernel(
    const float* __restrict__ X,
    const float* __restrict__ E,
    const float* __restrict__ ema_cs,
    const float* __restrict__ ema_dw,
    const unsigned long long* __restrict__ keys,
    const float* __restrict__ nbuf,
    float* __restrict__ out,
    float* __restrict__ counts,
    float* __restrict__ lossp)
{
    __shared__ int queue[8][QCAP];       // 32KB
    __shared__ float redA[8][4][256];    // 32KB
    __shared__ float redL[8];
    __shared__ int redC[8][4];

    int k0 = blockIdx.x * 4;
    int tid = threadIdx.x;
    int w = tid >> 6, lane = tid & 63;

    // q4[j][slot] = E[(lane*4+j)*K + k0+slot] : 4 consecutive floats = float4
    float4 q4[4];
    #pragma unroll
    for (int j = 0; j < 4; ++j)
        q4[j] = *(const float4*)&E[(size_t)(lane * 4 + j) * K_CODES + k0];

    const float4* X4 = (const float4*)X;
    float4* O4 = (float4*)(out + OFF_QST);
    const ulonglong2* K2 = (const ulonglong2*)keys;

    float a0[4] = {0.f, 0.f, 0.f, 0.f}, a1[4] = {0.f, 0.f, 0.f, 0.f};
    float a2[4] = {0.f, 0.f, 0.f, 0.f}, a3[4] = {0.f, 0.f, 0.f, 0.f};
    float ls = 0.f;
    int cs0 = 0, cs1 = 0, cs2 = 0, cs3 = 0;
    int cnt = 0;
    unsigned long long below_mask = (lane == 0) ? 0ull : (~0ull >> (64 - lane));

#define ROWBODY(comp, A, CS) do {                                           \
        float d0 = q4[0].comp - x.x, d1 = q4[1].comp - x.y;                 \
        float d2 = q4[2].comp - x.z, d3 = q4[3].comp - x.w;                 \
        o.x = x.x + d0; o.y = x.y + d1; o.z = x.z + d2; o.w = x.w + d3;     \
        A[0] += x.x; A[1] += x.y; A[2] += x.z; A[3] += x.w;                 \
        dl = d0 * d0 + d1 * d1 + d2 * d2 + d3 * d3; CS += 1;                \
    } while (0)

#define DRAIN() do {                                                        \
        for (int qi = 0; qi < cnt; ++qi) {                                  \
            int e = queue[w][qi];                                           \
            int row = e >> 2;                                               \
            int s = e & 3;   /* wave-uniform */                             \
            float4 x = X4[(size_t)row * 64 + lane];                         \
            float4 o; float dl;                                             \
            if (s == 0)      ROWBODY(x, a0, cs0);                           \
            else if (s == 1) ROWBODY(y, a1, cs1);                           \
            else if (s == 2) ROWBODY(z, a2, cs2);                           \
            else             ROWBODY(w, a3, cs3);                           \
            O4[(size_t)row * 64 + lane] = o;                                \
            ls += dl;                                                       \
        }                                                                   \
        cnt = 0;                                                            \
    } while (0)

    int base = w * 2048;   // ulonglong2 units; wave eighth = 4096 keys
    for (int it = 0; it < 32; ++it) {
        ulonglong2 kv = K2[base + it * 64 + lane];
        int r0 = (base + it * 64 + lane) * 2;
        int i0 = (int)(0xffffffffu - (unsigned)(kv.x & 0xffffffffull));
        int i1 = (int)(0xffffffffu - (unsigned)(kv.y & 0xffffffffull));
        unsigned s0 = (unsigned)(i0 - k0);
        unsigned s1 = (unsigned)(i1 - k0);
        {
            bool p = s0 < 4u;
            unsigned long long m = __ballot(p);
            if (p) queue[w][cnt + __popcll(m & below_mask)] = (r0 << 2) | (int)s0;
            cnt += __popcll(m);
        }
        {
            bool p = s1 < 4u;
            unsigned long long m = __ballot(p);
            if (p) queue[w][cnt + __popcll(m & below_mask)] = ((r0 + 1) << 2) | (int)s1;
            cnt += __popcll(m);
        }
        if (cnt >= QCAP - 128) DRAIN();
    }
    DRAIN();
#undef DRAIN
#undef ROWBODY

    #pragma unroll
    for (int j = 0; j < 4; ++j) {
        redA[w][0][lane * 4 + j] = a0[j];
        redA[w][1][lane * 4 + j] = a1[j];
        redA[w][2][lane * 4 + j] = a2[j];
        redA[w][3][lane * 4 + j] = a3[j];
    }
    #pragma unroll
    for (int m = 1; m < 64; m <<= 1) ls += __shfl_xor(ls, m, 64);
    if (lane == 0) {
        redL[w] = ls;
        redC[w][0] = cs0; redC[w][1] = cs1; redC[w][2] = cs2; redC[w][3] = cs3;
    }
    __syncthreads();

    if (tid < 256) {
        float n = nbuf[0];
        float4 edw = *(const float4*)&ema_dw[(size_t)tid * K_CODES + k0];
        float dws[4], inv[4];
        #pragma unroll
        for (int s = 0; s < 4; ++s) {
            float d = 0.f;
            int c = 0;
            #pragma unroll
            for (int wv = 0; wv < 8; ++wv) { d += redA[wv][s][tid]; c += redC[wv][s]; }
            dws[s] = d;
            float cntf = (float)c;
            float necs = ema_cs[k0 + s] * DECAY_F + cntf * ONE_MINUS_DECAY;
            float sm = (necs + EPS_F) / (n + (float)K_CODES * EPS_F) * n;
            inv[s] = 1.0f / sm;
            if (tid == s) {   // threads 0..3 publish per-code scalars
                counts[k0 + s] = cntf;
                out[OFF_CS + k0 + s] = necs;
            }
        }
        float4 odw, oemb;
        odw.x = edw.x * DECAY_F + dws[0] * ONE_MINUS_DECAY; oemb.x = odw.x * inv[0];
        odw.y = edw.y * DECAY_F + dws[1] * ONE_MINUS_DECAY; oemb.y = odw.y * inv[1];
        odw.z = edw.z * DECAY_F + dws[2] * ONE_MINUS_DECAY; oemb.z = odw.z * inv[2];
        odw.w = edw.w * DECAY_F + dws[3] * ONE_MINUS_DECAY; oemb.w = odw.w * inv[3];
        *(float4*)&out[OFF_DW + (size_t)tid * K_CODES + k0] = odw;
        *(float4*)&out[OFF_EMB + (size_t)tid * K_CODES + k0] = oemb;
    }
    if (tid == 0) {
        float sl = 0.f;
        #pragma unroll
        for (int wv = 0; wv < 8; ++wv) sl += redL[wv];
        lossp[blockIdx.x] = sl;
    }
}

// ---------------- finalize: loss + perplexity scalars only ----------------
__global__ __launch_bounds__(1024) void finalize_kernel(const float* __restrict__ counts,
                                                        const float* __restrict__ lossp,
                                                        float* __restrict__ out) {
    __shared__ double partE[16], partL[16];
    int k = threadIdx.x;
    int lane = k & 63, wid = k >> 6;
    float cs = counts[k];
    float avg = cs * (1.0f / (float)N_ROWS);
    double ve = (double)(avg * logf(avg + 1e-10f));
    double vl = (k < 256) ? (double)lossp[k] : 0.0;
    #pragma unroll
    for (int m = 1; m < 64; m <<= 1) {
        ve += __shfl_xor(ve, m, 64);
        vl += __shfl_xor(vl, m, 64);
    }
    if (lane == 0) { partE[wid] = ve; partL[wid] = vl; }
    __syncthreads();
    if (k == 0) {
        double se = 0.0, sl = 0.0;
        #pragma unroll
        for (int i = 0; i < 16; ++i) { se += partE[i]; sl += partL[i]; }
        double eloss = sl / (double)(N_ROWS * C_DIM);
        out[OFF_LOSS] = (float)(0.25 * eloss);
        out[OFF_PERP] = expf((float)(-se));
    }
}

extern "C" void kernel_launch(void* const* d_in, const int* in_sizes, int n_in,
                              void* d_out, int out_size, void* d_ws, size_t ws_size,
                              hipStream_t stream) {
    const float* inputs = (const float*)d_in[0];
    const float* E      = (const float*)d_in[1];
    const float* ema_cs = (const float*)d_in[2];
    const float* ema_dw = (const float*)d_in[3];
    float* out = (float*)d_out;
    float* ws  = (float*)d_ws;

    float* esq    = ws + WS_ESQ;
    short* Bp     = (short*)(ws + WS_BP);
    float* counts = ws + WS_CNT;
    float* lossp  = ws + WS_LOSSP;
    float* nbuf   = ws + WS_NBUF;
    unsigned long long* keys = (unsigned long long*)(ws + WS_KEYS);

    prep_kernel<<<133, 256, 0, stream>>>(E, ema_cs, Bp, esq, keys, nbuf);
    mfma_dist_kernel<<<512, 256, 0, stream>>>(inputs, Bp, esq, keys);
    percode_kernel<<<K_CODES / 4, 512, 0, stream>>>(inputs, E, ema_cs, ema_dw,
                                                    keys, nbuf, out, counts, lossp);
    finalize_kernel<<<1, 1024, 0, stream>>>(counts, lossp, out);
}